// Round 1
// baseline (684.444 us; speedup 1.0000x reference)
//
#include <hip/hip_runtime.h>
#include <math.h>

#define BB   16
#define NN   2048
#define DIN  512
#define DKK  10
#define NHD  2
#define DH   5
#define HID  20
#define DOUT 512
#define BH   32          // BB*NHD
#define KC   256         // attention k-chunk
#define NKC  8           // NN/KC

// ws layout (floats):
//   qkv : [3][BH][NN][8]   (q pre-scaled by 1/sqrt(5); rows padded 5->8)
//   part: [NKC][BH][NN][8] (acc[0..4], denom at [5])
#define QKV_ELEMS ((size_t)3*BH*NN*8)

// ---------------------------------------------------------------- kernel 1
__global__ __launch_bounds__(64) void proj_kernel(
    const float* __restrict__ x,
    const float* __restrict__ Wq, const float* __restrict__ bq,
    const float* __restrict__ Wk, const float* __restrict__ bk,
    const float* __restrict__ Wv, const float* __restrict__ bv,
    float* __restrict__ qkv)
{
    const int lane = threadIdx.x;
    const int tok  = blockIdx.x*64 + lane;
    const int b    = tok >> 11;
    const int n    = tok & (NN-1);
    const float* xr = x + (size_t)tok*DIN;

    float accq[DKK], acck[DKK], accv[DKK];
    #pragma unroll
    for (int o=0;o<DKK;o++){ accq[o]=bq[o]; acck[o]=bk[o]; accv[o]=bv[o]; }

    // double-buffered 64B-per-lane x chunks (prefetch next line during compute)
    float4 A0,A1,A2,A3, B0,B1,B2,B3;
    A0 = *(const float4*)(xr+ 0); A1 = *(const float4*)(xr+ 4);
    A2 = *(const float4*)(xr+ 8); A3 = *(const float4*)(xr+12);

    #define DO16(V0,V1,V2,V3,JBASE) {                                   \
        float xs[16] = {V0.x,V0.y,V0.z,V0.w, V1.x,V1.y,V1.z,V1.w,       \
                        V2.x,V2.y,V2.z,V2.w, V3.x,V3.y,V3.z,V3.w};      \
        _Pragma("unroll")                                               \
        for (int t=0;t<16;t++){                                         \
            const int j = (JBASE)+t;                                    \
            const float xj = xs[t];                                     \
            _Pragma("unroll")                                           \
            for (int o=0;o<DKK;o++){                                    \
                accq[o] = fmaf(xj, Wq[j*DKK+o], accq[o]);               \
                acck[o] = fmaf(xj, Wk[j*DKK+o], acck[o]);               \
                accv[o] = fmaf(xj, Wv[j*DKK+o], accv[o]);               \
            }                                                           \
        } }

    for (int c=0; c<32; c+=2){
        const int jB = (c+1)*16;
        B0 = *(const float4*)(xr+jB+ 0); B1 = *(const float4*)(xr+jB+ 4);
        B2 = *(const float4*)(xr+jB+ 8); B3 = *(const float4*)(xr+jB+12);
        DO16(A0,A1,A2,A3, c*16);
        if (c+2 < 32){
            const int jA = (c+2)*16;
            A0 = *(const float4*)(xr+jA+ 0); A1 = *(const float4*)(xr+jA+ 4);
            A2 = *(const float4*)(xr+jA+ 8); A3 = *(const float4*)(xr+jA+12);
        }
        DO16(B0,B1,B2,B3, jB);
    }
    #undef DO16

    const float qs = 0.44721359549995793f;  // 1/sqrt(5): folded into Q
    float* qb = qkv;
    float* kb = qkv + (size_t)BH*NN*8;
    float* vb = kb  + (size_t)BH*NN*8;
    #pragma unroll
    for (int h=0;h<NHD;h++){
        const size_t base = (((size_t)(b*NHD+h))*NN + n)*8;
        *(float4*)(qb+base) = make_float4(accq[h*DH+0]*qs, accq[h*DH+1]*qs,
                                          accq[h*DH+2]*qs, accq[h*DH+3]*qs);
        qb[base+4] = accq[h*DH+4]*qs;
        *(float4*)(kb+base) = make_float4(acck[h*DH+0], acck[h*DH+1],
                                          acck[h*DH+2], acck[h*DH+3]);
        kb[base+4] = acck[h*DH+4];
        *(float4*)(vb+base) = make_float4(accv[h*DH+0], accv[h*DH+1],
                                          accv[h*DH+2], accv[h*DH+3]);
        vb[base+4] = accv[h*DH+4];
    }
}

// ---------------------------------------------------------------- kernel 2
// grid (qt=32, kc=8, bh=32), block 64. One q-row per lane, wave-uniform k.
// scores = sin(q.k/sqrt5) are in [-1,1] -> exp(sin) needs no max pass.
__global__ __launch_bounds__(64) void attn_kernel(
    const float* __restrict__ qkv, float* __restrict__ part)
{
    const int qt   = blockIdx.x;
    const int kc   = blockIdx.y;
    const int bh   = blockIdx.z;
    const int lane = threadIdx.x;
    const int qtile0 = qt*64;
    const int k0     = kc*KC;
    if (k0 > qtile0 + 63) return;          // uniform early-out (causal)

    const int q = qtile0 + lane;
    const float* qr = qkv + ((size_t)bh*NN + q)*8;
    const float4 qv = *(const float4*)qr;
    const float  q4 = qr[4];

    const float* kbase = qkv + (size_t)BH*NN*8 + (size_t)bh*NN*8;
    const float* vbase = kbase + (size_t)BH*NN*8;
    const int kend = (k0+KC < qtile0+64) ? (k0+KC) : (qtile0+64);  // uniform

    float denom=0.f, a0=0.f, a1=0.f, a2=0.f, a3=0.f, a4=0.f;
    #pragma unroll 4
    for (int k=k0; k<kend; ++k){
        const float* kr = kbase + (size_t)k*8;   // wave-uniform -> s_load
        const float* vr = vbase + (size_t)k*8;
        float s = qv.x*kr[0] + qv.y*kr[1] + qv.z*kr[2] + qv.w*kr[3] + q4*kr[4];
        float e = __expf(__sinf(s));
        e = (k <= q) ? e : 0.f;                  // causal mask, per-lane
        denom += e;
        a0 = fmaf(e, vr[0], a0);
        a1 = fmaf(e, vr[1], a1);
        a2 = fmaf(e, vr[2], a2);
        a3 = fmaf(e, vr[3], a3);
        a4 = fmaf(e, vr[4], a4);
    }
    float* pr = part + (((size_t)kc*BH + bh)*NN + q)*8;
    *(float4*)pr = make_float4(a0,a1,a2,a3);
    pr[4] = a4;
    pr[5] = denom;
}

// ---------------------------------------------------------------- kernel 3
// One wave handles half an output row (256 cols, 4 per lane) for 8 tokens;
// Wm2 column-slice lives in registers, stores are coalesced dwordx4.
__global__ __launch_bounds__(256) void mlp_kernel(
    const float* __restrict__ part,
    const float* __restrict__ Wm1, const float* __restrict__ bm1,
    const float* __restrict__ Wm2, const float* __restrict__ bm2,
    float* __restrict__ out)
{
    const int wave = threadIdx.x >> 6;
    const int lane = threadIdx.x & 63;
    const int unit = blockIdx.x*4 + wave;   // 0..8191
    const int hc   = unit & 1;              // which half of the 512 outputs
    const int tg   = unit >> 1;             // token group of 8
    const int o0   = hc*256 + lane*4;

    float4 w2[HID];
    #pragma unroll
    for (int j=0;j<HID;j++) w2[j] = *(const float4*)(Wm2 + j*DOUT + o0);
    const float4 b2 = *(const float4*)(bm2 + o0);

    for (int ti=0; ti<8; ++ti){
        const int tok = tg*8 + ti;
        const int b   = tok >> 11;
        const int n   = tok & (NN-1);

        float vals[DKK];
        #pragma unroll
        for (int h=0;h<NHD;h++){
            const int bh = b*NHD + h;
            float s0=0,s1=0,s2=0,s3=0,s4=0,sd=0;
            const int nc = (n >> 8) + 1;    // valid causal k-chunks
            for (int c=0;c<nc;c++){
                const float* pr = part + (((size_t)c*BH + bh)*NN + n)*8;  // uniform
                s0+=pr[0]; s1+=pr[1]; s2+=pr[2]; s3+=pr[3]; s4+=pr[4]; sd+=pr[5];
            }
            const float inv = 1.0f / sd;
            vals[h*DH+0]=s0*inv; vals[h*DH+1]=s1*inv; vals[h*DH+2]=s2*inv;
            vals[h*DH+3]=s3*inv; vals[h*DH+4]=s4*inv;
        }

        float h1[HID];
        #pragma unroll
        for (int jo=0;jo<HID;jo++){
            float t = bm1[jo];
            #pragma unroll
            for (int d=0;d<DKK;d++) t = fmaf(vals[d], Wm1[d*HID+jo], t);
            h1[jo] = (t > 0.f) ? t : 0.01f*t;   // leaky_relu
        }

        float4 acc = b2;
        #pragma unroll
        for (int j=0;j<HID;j++){
            acc.x = fmaf(h1[j], w2[j].x, acc.x);
            acc.y = fmaf(h1[j], w2[j].y, acc.y);
            acc.z = fmaf(h1[j], w2[j].z, acc.z);
            acc.w = fmaf(h1[j], w2[j].w, acc.w);
        }
        *(float4*)(out + (size_t)tok*DOUT + o0) = acc;
    }
}

// ---------------------------------------------------------------- launch
extern "C" void kernel_launch(void* const* d_in, const int* in_sizes, int n_in,
                              void* d_out, int out_size, void* d_ws, size_t ws_size,
                              hipStream_t stream) {
    const float* x   = (const float*)d_in[0];
    const float* Wq  = (const float*)d_in[1];
    const float* bq  = (const float*)d_in[2];
    const float* Wk  = (const float*)d_in[3];
    const float* bk  = (const float*)d_in[4];
    const float* Wv  = (const float*)d_in[5];
    const float* bv  = (const float*)d_in[6];
    const float* Wm1 = (const float*)d_in[7];
    const float* bm1 = (const float*)d_in[8];
    const float* Wm2 = (const float*)d_in[9];
    const float* bm2 = (const float*)d_in[10];
    float* out = (float*)d_out;

    float* qkv  = (float*)d_ws;
    float* part = qkv + QKV_ELEMS;
    // every part[] slot kernel 3 reads is written by kernel 2 each call:
    // no memset needed, re-poison safe.

    proj_kernel<<<dim3(512), dim3(64), 0, stream>>>(x, Wq,bq, Wk,bk, Wv,bv, qkv);
    attn_kernel<<<dim3(32, NKC, BH), dim3(64), 0, stream>>>(qkv, part);
    mlp_kernel<<<dim3(2048), dim3(256), 0, stream>>>(part, Wm1,bm1, Wm2,bm2, out);
}